// Round 1
// baseline (110.252 us; speedup 1.0000x reference)
//
#include <hip/hip_runtime.h>

#define NN 1024
#define HH 128
#define CC 7

// ---------------- Kernel A: P = e@mW1[0:H] + mb1 ; Q = e@mW1[H:2H] ----------
__global__ __launch_bounds__(128) void precompute_pq(
    const float* __restrict__ e, const float* __restrict__ mW1,
    const float* __restrict__ mb1, float* __restrict__ P, float* __restrict__ Q)
{
    const int h  = threadIdx.x;
    const int i0 = blockIdx.x * 8;
    __shared__ float eL[8][HH];
    #pragma unroll
    for (int r = 0; r < 8; ++r) eL[r][h] = e[(i0 + r) * HH + h];
    __syncthreads();
    float p[8], q[8];
    const float b = mb1[h];
    #pragma unroll
    for (int r = 0; r < 8; ++r) { p[r] = b; q[r] = 0.f; }
    for (int k = 0; k < HH; ++k) {
        const float w1 = mW1[k * HH + h];
        const float w2 = mW1[(HH + k) * HH + h];
        #pragma unroll
        for (int r = 0; r < 8; ++r) {
            p[r] = fmaf(eL[r][k], w1, p[r]);
            q[r] = fmaf(eL[r][k], w2, q[r]);
        }
    }
    #pragma unroll
    for (int r = 0; r < 8; ++r) {
        P[(i0 + r) * HH + h] = p[r];
        Q[(i0 + r) * HH + h] = q[r];
    }
}

// ---------------- Kernel B: HS[i,h] = sum_j relu(P[i,h]+Q[j,h]+c[i,j,:]@Cw[:,h])
__global__ __launch_bounds__(256) void msg_sum(
    const float* __restrict__ c, const float* __restrict__ mW1,
    const float* __restrict__ P, const float* __restrict__ Q,
    float* __restrict__ HS)
{
    const int i = blockIdx.x;
    const int t = threadIdx.x;
    const int h = t & (HH - 1);
    const int s = t >> 7;                 // j-slice 0/1
    __shared__ float cbuf[64 * CC];       // 448 floats
    __shared__ float red[HH];

    float cw[CC];
    #pragma unroll
    for (int k = 0; k < CC; ++k) cw[k] = mW1[(2 * HH + k) * HH + h];

    const float base = P[i * HH + h];     // mb1 already folded in
    const float* __restrict__ crow = c + (size_t)i * NN * CC;

    float acc = 0.f;
    for (int jc = 0; jc < NN; jc += 64) {
        __syncthreads();
        for (int idx = t; idx < 64 * CC; idx += 256)
            cbuf[idx] = crow[(size_t)jc * CC + idx];
        __syncthreads();
        const int j0 = jc + s * 32;
        #pragma unroll 8
        for (int jj = 0; jj < 32; ++jj) {
            const int j = j0 + jj;
            float v = base + Q[j * HH + h];
            const float* cp = cbuf + (j - jc) * CC;   // same addr across lanes: broadcast
            #pragma unroll
            for (int k = 0; k < CC; ++k) v = fmaf(cp[k], cw[k], v);
            acc += fmaxf(v, 0.f);
        }
    }
    if (s == 1) red[h] = acc;
    __syncthreads();
    if (s == 0) HS[i * HH + h] = acc + red[h];
}

// ---------------- Kernel C: agg = HS@mW2 + N*mb2 ; u=[agg,e] ; out = relu(u@uW1+ub1)@uW2+ub2
__global__ __launch_bounds__(128) void final_mlp(
    const float* __restrict__ e, const float* __restrict__ HS,
    const float* __restrict__ mW2, const float* __restrict__ mb2,
    const float* __restrict__ uW1, const float* __restrict__ ub1,
    const float* __restrict__ uW2, const float* __restrict__ ub2,
    float* __restrict__ out)
{
    const int h  = threadIdx.x;
    const int i0 = blockIdx.x * 8;
    __shared__ float hsL[8][HH], eL[8][HH], aggL[8][HH], t1L[8][HH];
    #pragma unroll
    for (int r = 0; r < 8; ++r) {
        hsL[r][h] = HS[(i0 + r) * HH + h];
        eL[r][h]  = e[(i0 + r) * HH + h];
    }
    __syncthreads();

    // stage 1: agg
    float a[8];
    const float b2 = (float)NN * mb2[h];
    #pragma unroll
    for (int r = 0; r < 8; ++r) a[r] = b2;
    for (int k = 0; k < HH; ++k) {
        const float w = mW2[k * HH + h];
        #pragma unroll
        for (int r = 0; r < 8; ++r) a[r] = fmaf(hsL[r][k], w, a[r]);
    }
    #pragma unroll
    for (int r = 0; r < 8; ++r) aggL[r][h] = a[r];
    __syncthreads();

    // stage 2: t1 = relu([agg,e]@uW1 + ub1)
    float t1[8];
    const float b3 = ub1[h];
    #pragma unroll
    for (int r = 0; r < 8; ++r) t1[r] = b3;
    for (int k = 0; k < HH; ++k) {
        const float w1 = uW1[k * HH + h];
        const float w2 = uW1[(HH + k) * HH + h];
        #pragma unroll
        for (int r = 0; r < 8; ++r) {
            t1[r] = fmaf(aggL[r][k], w1, t1[r]);
            t1[r] = fmaf(eL[r][k],  w2, t1[r]);
        }
    }
    #pragma unroll
    for (int r = 0; r < 8; ++r) t1L[r][h] = fmaxf(t1[r], 0.f);
    __syncthreads();

    // stage 3: out = t1@uW2 + ub2
    float o[8];
    const float b4 = ub2[h];
    #pragma unroll
    for (int r = 0; r < 8; ++r) o[r] = b4;
    for (int k = 0; k < HH; ++k) {
        const float w = uW2[k * HH + h];
        #pragma unroll
        for (int r = 0; r < 8; ++r) o[r] = fmaf(t1L[r][k], w, o[r]);
    }
    #pragma unroll
    for (int r = 0; r < 8; ++r) out[(i0 + r) * HH + h] = o[r];
}

extern "C" void kernel_launch(void* const* d_in, const int* in_sizes, int n_in,
                              void* d_out, int out_size, void* d_ws, size_t ws_size,
                              hipStream_t stream) {
    const float* e   = (const float*)d_in[0];
    const float* c   = (const float*)d_in[1];
    const float* mW1 = (const float*)d_in[2];
    const float* mb1 = (const float*)d_in[3];
    const float* mW2 = (const float*)d_in[4];
    const float* mb2 = (const float*)d_in[5];
    const float* uW1 = (const float*)d_in[6];
    const float* ub1 = (const float*)d_in[7];
    const float* uW2 = (const float*)d_in[8];
    const float* ub2 = (const float*)d_in[9];
    float* out = (float*)d_out;

    float* P  = (float*)d_ws;            // N*H
    float* Q  = P + NN * HH;             // N*H
    float* HS = Q + NN * HH;             // N*H   (total 1.5 MB of d_ws)

    precompute_pq<<<NN / 8, 128, 0, stream>>>(e, mW1, mb1, P, Q);
    msg_sum<<<NN, 256, 0, stream>>>(c, mW1, P, Q, HS);
    final_mlp<<<NN / 8, 128, 0, stream>>>(e, HS, mW2, mb2, uW1, ub1, uW2, ub2, out);
}

// Round 2
// 78.035 us; speedup vs baseline: 1.4128x; 1.4128x over previous
//
#include <hip/hip_runtime.h>

#define NN 1024
#define HH 128
#define CC 7

// ---------------- Kernel A: P = e@mW1[0:H] + mb1 ; Q = e@mW1[H:2H] ----------
__global__ __launch_bounds__(128) void precompute_pq(
    const float* __restrict__ e, const float* __restrict__ mW1,
    const float* __restrict__ mb1, float* __restrict__ P, float* __restrict__ Q)
{
    const int h  = threadIdx.x;
    const int i0 = blockIdx.x * 4;
    __shared__ float eL[4][HH];
    #pragma unroll
    for (int r = 0; r < 4; ++r) eL[r][h] = e[(i0 + r) * HH + h];
    __syncthreads();
    float p[4], q[4];
    const float b = mb1[h];
    #pragma unroll
    for (int r = 0; r < 4; ++r) { p[r] = b; q[r] = 0.f; }
    for (int k = 0; k < HH; ++k) {
        const float w1 = mW1[k * HH + h];
        const float w2 = mW1[(HH + k) * HH + h];
        #pragma unroll
        for (int r = 0; r < 4; ++r) {
            p[r] = fmaf(eL[r][k], w1, p[r]);
            q[r] = fmaf(eL[r][k], w2, q[r]);
        }
    }
    #pragma unroll
    for (int r = 0; r < 4; ++r) {
        P[(i0 + r) * HH + h] = p[r];
        Q[(i0 + r) * HH + h] = q[r];
    }
}

// ---------------- Kernel B: partial HS over half the j-range per block ------
// HSp[jhalf][i][h] = sum_{j in half} relu(P[i,h] + Q[j,h] + c[i,j,:]@Cw[:,h])
__global__ __launch_bounds__(256) void msg_sum2(
    const float* __restrict__ c, const float* __restrict__ mW1,
    const float* __restrict__ P, const float* __restrict__ Q,
    float* __restrict__ HSp)
{
    const int bid   = blockIdx.x;
    const int i     = bid >> 1;
    const int jhalf = bid & 1;
    const int t     = threadIdx.x;
    const int wav   = t >> 6;
    const int lane  = t & 63;
    const int hh    = lane + ((wav & 1) << 6);   // 0..127
    const int jq    = wav >> 1;                  // j-quarter within half: 0/1
    // wave-uniform j base, forced into an SGPR so c-loads scalarize
    const int jbase = __builtin_amdgcn_readfirstlane(jhalf * 512 + jq * 256);

    float cw[CC];
    #pragma unroll
    for (int k = 0; k < CC; ++k) cw[k] = mW1[(2 * HH + k) * HH + hh];
    const float base = P[i * HH + hh];           // mb1 folded in
    const float* __restrict__ qcol = Q + hh;
    const float* __restrict__ crow = c + ((size_t)i * NN + jbase) * CC;

    float acc = 0.f;
    for (int jo = 0; jo < 256; jo += 8) {
        const float* __restrict__ cb = crow + jo * CC;   // wave-uniform ptr
        #pragma unroll
        for (int u = 0; u < 8; ++u) {
            float v = base + qcol[(size_t)(jbase + jo + u) * HH];
            #pragma unroll
            for (int k = 0; k < CC; ++k)
                v = fmaf(cb[u * CC + k], cw[k], v);
            acc += fmaxf(v, 0.f);
        }
    }

    __shared__ float red[HH];
    if (jq == 1) red[hh] = acc;
    __syncthreads();
    if (jq == 0) HSp[((size_t)jhalf * NN + i) * HH + hh] = acc + red[hh];
}

// ---------------- Kernel C: agg -> u -> out ---------------------------------
__global__ __launch_bounds__(128) void final_mlp(
    const float* __restrict__ e, const float* __restrict__ HSp,
    const float* __restrict__ mW2, const float* __restrict__ mb2,
    const float* __restrict__ uW1, const float* __restrict__ ub1,
    const float* __restrict__ uW2, const float* __restrict__ ub2,
    float* __restrict__ out)
{
    const int h  = threadIdx.x;
    const int i0 = blockIdx.x * 4;
    __shared__ float hsL[4][HH], eL[4][HH], aggL[4][HH], t1L[4][HH];
    #pragma unroll
    for (int r = 0; r < 4; ++r) {
        const size_t ih = (size_t)(i0 + r) * HH + h;
        hsL[r][h] = HSp[ih] + HSp[(size_t)NN * HH + ih];
        eL[r][h]  = e[ih];
    }
    __syncthreads();

    // stage 1: agg = HS@mW2 + N*mb2
    float a[4];
    const float b2 = (float)NN * mb2[h];
    #pragma unroll
    for (int r = 0; r < 4; ++r) a[r] = b2;
    for (int k = 0; k < HH; ++k) {
        const float w = mW2[k * HH + h];
        #pragma unroll
        for (int r = 0; r < 4; ++r) a[r] = fmaf(hsL[r][k], w, a[r]);
    }
    #pragma unroll
    for (int r = 0; r < 4; ++r) aggL[r][h] = a[r];
    __syncthreads();

    // stage 2: t1 = relu([agg, e] @ uW1 + ub1)
    float t1[4];
    const float b3 = ub1[h];
    #pragma unroll
    for (int r = 0; r < 4; ++r) t1[r] = b3;
    for (int k = 0; k < HH; ++k) {
        const float w1 = uW1[k * HH + h];
        const float w2 = uW1[(HH + k) * HH + h];
        #pragma unroll
        for (int r = 0; r < 4; ++r) {
            t1[r] = fmaf(aggL[r][k], w1, t1[r]);
            t1[r] = fmaf(eL[r][k],  w2, t1[r]);
        }
    }
    #pragma unroll
    for (int r = 0; r < 4; ++r) t1L[r][h] = fmaxf(t1[r], 0.f);
    __syncthreads();

    // stage 3: out = t1 @ uW2 + ub2
    float o[4];
    const float b4 = ub2[h];
    #pragma unroll
    for (int r = 0; r < 4; ++r) o[r] = b4;
    for (int k = 0; k < HH; ++k) {
        const float w = uW2[k * HH + h];
        #pragma unroll
        for (int r = 0; r < 4; ++r) o[r] = fmaf(t1L[r][k], w, o[r]);
    }
    #pragma unroll
    for (int r = 0; r < 4; ++r) out[(size_t)(i0 + r) * HH + h] = o[r];
}

extern "C" void kernel_launch(void* const* d_in, const int* in_sizes, int n_in,
                              void* d_out, int out_size, void* d_ws, size_t ws_size,
                              hipStream_t stream) {
    const float* e   = (const float*)d_in[0];
    const float* c   = (const float*)d_in[1];
    const float* mW1 = (const float*)d_in[2];
    const float* mb1 = (const float*)d_in[3];
    const float* mW2 = (const float*)d_in[4];
    const float* mb2 = (const float*)d_in[5];
    const float* uW1 = (const float*)d_in[6];
    const float* ub1 = (const float*)d_in[7];
    const float* uW2 = (const float*)d_in[8];
    const float* ub2 = (const float*)d_in[9];
    float* out = (float*)d_out;

    float* P   = (float*)d_ws;              // N*H
    float* Q   = P + NN * HH;               // N*H
    float* HSp = Q + NN * HH;               // 2*N*H  (total 2 MB of d_ws)

    precompute_pq<<<NN / 4, 128, 0, stream>>>(e, mW1, mb1, P, Q);
    msg_sum2<<<NN * 2, 256, 0, stream>>>(c, mW1, P, Q, HSp);
    final_mlp<<<NN / 4, 128, 0, stream>>>(e, HSp, mW2, mb2, uW1, ub1, uW2, ub2, out);
}